// Round 3
// baseline (451.600 us; speedup 1.0000x reference)
//
#include <hip/hip_runtime.h>
#include <stdint.h>

typedef unsigned short u16;
typedef __bf16 bf16x8 __attribute__((ext_vector_type(8)));
typedef float f32x4 __attribute__((ext_vector_type(4)));

#define GLD16(gp, lp) __builtin_amdgcn_global_load_lds( \
    (__attribute__((address_space(1))) void*)(uintptr_t)(gp), \
    (__attribute__((address_space(3))) void*)(uintptr_t)(lp), 16, 0, 0)

#define WAITVM8() asm volatile("s_waitcnt vmcnt(8)" ::: "memory")
#define BARRIER() asm volatile("s_barrier" ::: "memory")

__device__ __forceinline__ u16 f2bf(float f) {
  uint32_t u = __builtin_bit_cast(uint32_t, f);
  u += 0x7FFFu + ((u >> 16) & 1u);
  return (u16)(u >> 16);
}

// ---------------- weight transpose + convert: w[K][N] f32 -> wt[N][K] bf16 ----------
__global__ __launch_bounds__(256) void wtrans(const float* __restrict__ w,
                                              u16* __restrict__ wt, int K, int Nn) {
  __shared__ float tile[64][68];
  const int c0 = blockIdx.x << 6, r0 = blockIdx.y << 6;
  const int t = threadIdx.x, tr = t >> 2, tc = t & 3;
#pragma unroll
  for (int p = 0; p < 4; ++p) {
    float4 v = *(const float4*)&w[(size_t)(r0 + tr) * Nn + c0 + tc * 4 + p * 16];
    tile[tr][tc * 4 + p * 16 + 0] = v.x;
    tile[tr][tc * 4 + p * 16 + 1] = v.y;
    tile[tr][tc * 4 + p * 16 + 2] = v.z;
    tile[tr][tc * 4 + p * 16 + 3] = v.w;
  }
  __syncthreads();
#pragma unroll
  for (int p = 0; p < 4; ++p) {
    u16 e0 = f2bf(tile[tc * 4 + p * 16 + 0][tr]);
    u16 e1 = f2bf(tile[tc * 4 + p * 16 + 1][tr]);
    u16 e2 = f2bf(tile[tc * 4 + p * 16 + 2][tr]);
    u16 e3 = f2bf(tile[tc * 4 + p * 16 + 3][tr]);
    uint2 o;
    o.x = (uint32_t)e0 | ((uint32_t)e1 << 16);
    o.y = (uint32_t)e2 | ((uint32_t)e3 << 16);
    *(uint2*)&wt[(size_t)(c0 + tr) * K + r0 + tc * 4 + p * 16] = o;
  }
}

// ---------------- LayerNorm: x[M][1024] f32 -> out bf16 ----------------------------
__global__ __launch_bounds__(256) void lnorm(const float* x, const float* __restrict__ g,
                                             const float* __restrict__ bta,
                                             u16* __restrict__ out) {
  const int lane = threadIdx.x & 63, wid = threadIdx.x >> 6;
  const size_t token = (size_t)blockIdx.x * 4 + wid;
  const float* row = x + token * 1024;
  float v[16];
#pragma unroll
  for (int i = 0; i < 4; ++i) {
    float4 f = *(const float4*)&row[(lane + i * 64) * 4];
    v[i * 4 + 0] = f.x; v[i * 4 + 1] = f.y; v[i * 4 + 2] = f.z; v[i * 4 + 3] = f.w;
  }
  float s = 0.f, s2 = 0.f;
#pragma unroll
  for (int i = 0; i < 16; ++i) { s += v[i]; s2 += v[i] * v[i]; }
  for (int off = 1; off < 64; off <<= 1) {
    s += __shfl_xor(s, off);
    s2 += __shfl_xor(s2, off);
  }
  const float mu = s * (1.0f / 1024.0f);
  const float var = s2 * (1.0f / 1024.0f) - mu * mu;
  const float rstd = rsqrtf(var + 1e-6f);
  u16* orow = out + token * 1024;
#pragma unroll
  for (int i = 0; i < 4; ++i) {
    const int c = (lane + i * 64) * 4;
    float4 gv = *(const float4*)&g[c];
    float4 bv = *(const float4*)&bta[c];
    u16 e0 = f2bf((v[i * 4 + 0] - mu) * rstd * gv.x + bv.x);
    u16 e1 = f2bf((v[i * 4 + 1] - mu) * rstd * gv.y + bv.y);
    u16 e2 = f2bf((v[i * 4 + 2] - mu) * rstd * gv.z + bv.z);
    u16 e3 = f2bf((v[i * 4 + 3] - mu) * rstd * gv.w + bv.w);
    uint2 o;
    o.x = (uint32_t)e0 | ((uint32_t)e1 << 16);
    o.y = (uint32_t)e2 | ((uint32_t)e3 << 16);
    *(uint2*)&orow[c] = o;
  }
}

// ---------------- GEMM: C[M][N] = A[M][K](bf16) * Bt[N][K](bf16)^T + bias ----------
// 4-slot LDS ring, 3-tile prefetch, counted vmcnt(8) -- never drains to 0.
// EPI 0: +bias (cols<qlimit scaled by qscale) -> bf16 ; 1: +bias, GELU -> bf16 ;
// EPI 2: +bias +res -> f32
template <int EPI>
__global__ __launch_bounds__(256) void gemm128(const u16* __restrict__ A,
                                               const u16* __restrict__ Bt,
                                               const float* __restrict__ bias,
                                               const float* res, void* Cout,
                                               int Ndim, int K, float qscale, int qlimit) {
  __shared__ __align__(16) u16 ldsA[4][4096];
  __shared__ __align__(16) u16 ldsB[4][4096];
  const int tid = threadIdx.x;
  const int lane = tid & 63;
  const int wid = tid >> 6;
  const int wm = wid & 1, wn = wid >> 1;
  const int m0 = blockIdx.y << 7, n0 = blockIdx.x << 7;

  const int srow = lane >> 2;
  const int slc = (lane & 3) ^ ((srow ^ (srow >> 2)) & 3);
  const u16* Ag = A + (size_t)(m0 + 32 * wid + srow) * K + slc * 8;
  const u16* Bg = Bt + (size_t)(n0 + 32 * wid + srow) * K + slc * 8;
  const size_t rstep = (size_t)16 * K;

  const int rrow = lane & 15;
  const int rc = ((lane >> 4) ^ ((rrow ^ (rrow >> 2)) & 3)) * 16;

  const f32x4 fzero = {0.f, 0.f, 0.f, 0.f};
  f32x4 acc[4][4];
#pragma unroll
  for (int i = 0; i < 4; ++i)
#pragma unroll
    for (int j = 0; j < 4; ++j) acc[i][j] = fzero;

  const int nk = K >> 5;

#define GSTAGE(kt, s) do { \
    const u16* a_ = Ag + (size_t)(kt) * 32; \
    const u16* b_ = Bg + (size_t)(kt) * 32; \
    GLD16(a_, &ldsA[s][(2 * wid + 0) * 512]); \
    GLD16(a_ + rstep, &ldsA[s][(2 * wid + 1) * 512]); \
    GLD16(b_, &ldsB[s][(2 * wid + 0) * 512]); \
    GLD16(b_ + rstep, &ldsB[s][(2 * wid + 1) * 512]); \
  } while (0)

  GSTAGE(0, 0);
  GSTAGE(1, 1);
  GSTAGE(2, 2);
  for (int kt = 0; kt < nk; ++kt) {
    WAITVM8();   // retire exactly tile kt's 4 loads (kt+1,kt+2 stay in flight)
    BARRIER();   // publish DMA results to all waves; also guards slot reuse below
    if (kt + 3 < nk) GSTAGE(kt + 3, (kt + 3) & 3);  // slot last read at iter kt-1
    const int slot = kt & 3;
    bf16x8 af[4], bfr[4];
#pragma unroll
    for (int mf = 0; mf < 4; ++mf)
      af[mf] = *(const bf16x8*)((const char*)&ldsA[slot][0] +
                                (wm * 64 + mf * 16 + rrow) * 64 + rc);
#pragma unroll
    for (int nf = 0; nf < 4; ++nf)
      bfr[nf] = *(const bf16x8*)((const char*)&ldsB[slot][0] +
                                 (wn * 64 + nf * 16 + rrow) * 64 + rc);
#pragma unroll
    for (int mf = 0; mf < 4; ++mf)
#pragma unroll
      for (int nf = 0; nf < 4; ++nf)
        acc[mf][nf] =
            __builtin_amdgcn_mfma_f32_16x16x32_bf16(af[mf], bfr[nf], acc[mf][nf], 0, 0, 0);
  }
  const int g4 = (lane >> 4) << 2;
  const float cs = (EPI == 0 && n0 < qlimit) ? qscale : 1.0f;
#pragma unroll
  for (int nf = 0; nf < 4; ++nf) {
    const int col = n0 + wn * 64 + nf * 16 + rrow;
    const float bv = bias[col];
#pragma unroll
    for (int mf = 0; mf < 4; ++mf) {
#pragma unroll
      for (int r = 0; r < 4; ++r) {
        const int row = m0 + wm * 64 + mf * 16 + g4 + r;
        float v = acc[mf][nf][r] + bv;
        if (EPI == 0) v *= cs;
        if (EPI == 1) v = 0.5f * v * (1.0f + erff(v * 0.70710678118654752f));
        if (EPI == 2) {
          v += res[(size_t)row * Ndim + col];
          ((float*)Cout)[(size_t)row * Ndim + col] = v;
        } else {
          ((u16*)Cout)[(size_t)row * Ndim + col] = f2bf(v);
        }
      }
    }
  }
#undef GSTAGE
}

// ---------------- V transpose: qkv V block -> vt[bh][d][n] bf16 --------------------
__global__ __launch_bounds__(256) void vtrans(const u16* __restrict__ qkv,
                                              u16* __restrict__ vt) {
  const int bh = blockIdx.y, b = bh >> 4, h = bh & 15;
  const int n0 = blockIdx.x << 6;
  __shared__ __align__(16) u16 tile[64][72];
  const int t = threadIdx.x, r = t >> 2, c = t & 3;
  const u16* src = qkv + (size_t)((b << 10) + n0 + r) * 3072 + 2048 + (h << 6);
#pragma unroll
  for (int p = 0; p < 2; ++p)
    *(uint4*)&tile[r][(c * 2 + p) * 8] = *(const uint4*)(src + (c * 2 + p) * 8);
  __syncthreads();
  u16* dst = vt + (size_t)((bh << 6) + r) * 1024 + n0;
#pragma unroll
  for (int p = 0; p < 2; ++p) {
    u16 o[8];
#pragma unroll
    for (int j = 0; j < 8; ++j) o[j] = tile[(c * 2 + p) * 8 + j][r];
    uint4 w;
    w.x = (uint32_t)o[0] | ((uint32_t)o[1] << 16);
    w.y = (uint32_t)o[2] | ((uint32_t)o[3] << 16);
    w.z = (uint32_t)o[4] | ((uint32_t)o[5] << 16);
    w.w = (uint32_t)o[6] | ((uint32_t)o[7] << 16);
    *(uint4*)&dst[(c * 2 + p) * 8] = w;
  }
}

// ---------------- flash attention (no-max softmax, swapped QK^T, ring pipeline) ----
__global__ __launch_bounds__(256) void attn64(const u16* __restrict__ qkv,
                                              const u16* __restrict__ vt,
                                              u16* __restrict__ aout) {
  const int bh = blockIdx.y, b = bh >> 4, h = bh & 15;
  const int q0 = blockIdx.x << 6;
  const int tid = threadIdx.x, lane = tid & 63, wid = tid >> 6;
  __shared__ __align__(16) u16 kl[4][4096];
  __shared__ __align__(16) u16 vl[4][4096];
  __shared__ __align__(16) u16 pl[4][1152];  // [wave][16 q][72]: P rows, k-major

  const int rrow = lane & 15;
  const int g = lane >> 4;
  const u16* qrow = qkv + (size_t)((b << 10) + q0 + (wid << 4) + rrow) * 3072 + (h << 6);
  bf16x8 qf0 = *(const bf16x8*)(qrow + (g << 3));
  bf16x8 qf1 = *(const bf16x8*)(qrow + 32 + (g << 3));

  const int sr = lane >> 3;
  const int lc = (lane & 7) ^ sr;
  const u16* kbase = qkv + (size_t)(b << 10) * 3072 + 1024 + (h << 6) +
                     (size_t)(16 * wid + sr) * 3072 + lc * 8;
  const u16* vbase = vt + (size_t)(bh << 6) * 1024 + (size_t)(16 * wid + sr) * 1024 + lc * 8;

  const f32x4 fzero = {0.f, 0.f, 0.f, 0.f};
  f32x4 oacc[4];
#pragma unroll
  for (int i = 0; i < 4; ++i) oacc[i] = fzero;
  f32x4 lacc = fzero;
  const int rcb = lane & 7;
  u16* plw = &pl[wid][0];

#define ASTAGE(t, s) do { \
    const int kt0_ = (t) << 6; \
    GLD16(kbase + (size_t)kt0_ * 3072, &kl[s][(2 * wid + 0) * 512]); \
    GLD16(kbase + (size_t)kt0_ * 3072 + 8 * 3072, &kl[s][(2 * wid + 1) * 512]); \
    GLD16(vbase + kt0_, &vl[s][(2 * wid + 0) * 512]); \
    GLD16(vbase + kt0_ + 8 * 1024, &vl[s][(2 * wid + 1) * 512]); \
  } while (0)

  ASTAGE(0, 0);
  ASTAGE(1, 1);
  ASTAGE(2, 2);
  for (int t = 0; t < 16; ++t) {
    WAITVM8();
    BARRIER();
    if (t + 3 < 16) ASTAGE(t + 3, (t + 3) & 3);
    const int slot = t & 3;
    const char* klp = (const char*)&kl[slot][0];
    const char* vlp = (const char*)&vl[slot][0];

    f32x4 s4[4];
#pragma unroll
    for (int i = 0; i < 4; ++i) s4[i] = fzero;
#pragma unroll
    for (int nf = 0; nf < 4; ++nf) {
      bf16x8 k0 = *(const bf16x8*)(klp + (nf * 16 + rrow) * 128 + ((g + 0) ^ rcb) * 16);
      bf16x8 k1 = *(const bf16x8*)(klp + (nf * 16 + rrow) * 128 + ((g + 4) ^ rcb) * 16);
      s4[nf] = __builtin_amdgcn_mfma_f32_16x16x32_bf16(k0, qf0, s4[nf], 0, 0, 0);
      s4[nf] = __builtin_amdgcn_mfma_f32_16x16x32_bf16(k1, qf1, s4[nf], 0, 0, 0);
    }

    // softmax-lite: p = exp2(s); lane-local l accumulation; pack to bf16 pairs.
#pragma unroll
    for (int nf = 0; nf < 4; ++nf) {
      float p0 = exp2f(s4[nf][0]);
      float p1 = exp2f(s4[nf][1]);
      float p2 = exp2f(s4[nf][2]);
      float p3 = exp2f(s4[nf][3]);
      f32x4 pv = {p0, p1, p2, p3};
      lacc += pv;
      uint32_t a0 = __builtin_bit_cast(uint32_t, p0) + 0x8000u;
      uint32_t a1 = __builtin_bit_cast(uint32_t, p1) + 0x8000u;
      uint32_t a2 = __builtin_bit_cast(uint32_t, p2) + 0x8000u;
      uint32_t a3 = __builtin_bit_cast(uint32_t, p3) + 0x8000u;
      uint2 w;
      w.x = __builtin_amdgcn_perm(a1, a0, 0x07060302);
      w.y = __builtin_amdgcn_perm(a3, a2, 0x07060302);
      *(uint2*)(plw + rrow * 72 + nf * 16 + (g << 2)) = w;
    }

    bf16x8 pf0 = *(const bf16x8*)((const char*)plw + rrow * 144 + (g << 4));
    bf16x8 pf1 = *(const bf16x8*)((const char*)plw + rrow * 144 + (g << 4) + 64);
#pragma unroll
    for (int nf = 0; nf < 4; ++nf) {
      bf16x8 v0 = *(const bf16x8*)(vlp + (nf * 16 + rrow) * 128 + ((g + 0) ^ rcb) * 16);
      bf16x8 v1 = *(const bf16x8*)(vlp + (nf * 16 + rrow) * 128 + ((g + 4) ^ rcb) * 16);
      oacc[nf] = __builtin_amdgcn_mfma_f32_16x16x32_bf16(pf0, v0, oacc[nf], 0, 0, 0);
      oacc[nf] = __builtin_amdgcn_mfma_f32_16x16x32_bf16(pf1, v1, oacc[nf], 0, 0, 0);
    }
  }
#undef ASTAGE

  float lsum = lacc[0] + lacc[1] + lacc[2] + lacc[3];
  lsum += __shfl_xor(lsum, 16);
  lsum += __shfl_xor(lsum, 32);
  const float inv = 1.0f / lsum;
  float invq[4];
#pragma unroll
  for (int r = 0; r < 4; ++r) {
    int bi = __builtin_amdgcn_ds_bpermute(((g << 2) + r) << 2,
                                          __builtin_bit_cast(int, inv));
    invq[r] = __builtin_bit_cast(float, bi);
  }
  u16* ob = aout + (size_t)((b << 10) + q0 + (wid << 4)) * 1024 + (h << 6);
#pragma unroll
  for (int nf = 0; nf < 4; ++nf)
#pragma unroll
    for (int r = 0; r < 4; ++r)
      ob[(size_t)(g * 4 + r) * 1024 + nf * 16 + rrow] = f2bf(oacc[nf][r] * invq[r]);
}

// ---------------- launcher ---------------------------------------------------------
extern "C" void kernel_launch(void* const* d_in, const int* in_sizes, int n_in,
                              void* d_out, int out_size, void* d_ws, size_t ws_size,
                              hipStream_t stream) {
  const float* x = (const float*)d_in[0];
  const float* ln1_g = (const float*)d_in[1];
  const float* ln1_b = (const float*)d_in[2];
  const float* w_qkv = (const float*)d_in[3];
  const float* b_qkv = (const float*)d_in[4];
  const float* w_o = (const float*)d_in[5];
  const float* b_o = (const float*)d_in[6];
  const float* ln2_g = (const float*)d_in[7];
  const float* ln2_b = (const float*)d_in[8];
  const float* w_fc1 = (const float*)d_in[9];
  const float* b_fc1 = (const float*)d_in[10];
  const float* w_fc2 = (const float*)d_in[11];
  const float* b_fc2 = (const float*)d_in[12];
  float* out = (float*)d_out;

  char* w = (char*)d_ws;
  u16* wqkvT = (u16*)w; w += (size_t)3072 * 1024 * 2;
  u16* woT   = (u16*)w; w += (size_t)1024 * 1024 * 2;
  u16* wfc1T = (u16*)w; w += (size_t)4096 * 1024 * 2;
  u16* wfc2T = (u16*)w; w += (size_t)1024 * 4096 * 2;
  u16* xn    = (u16*)w; w += (size_t)8192 * 1024 * 2;
  u16* qkvb  = (u16*)w; w += (size_t)8192 * 3072 * 2;
  u16* vtb   = (u16*)w; w += (size_t)128 * 64 * 1024 * 2;
  u16* attnb = (u16*)w; w += (size_t)8192 * 1024 * 2;
  u16* hbuf  = qkvb;  // overlay: qkv+vt dead when h is produced

  const float QS = 0.18033688011112042f;  // 0.125 * log2(e)

  wtrans<<<dim3(48, 16), 256, 0, stream>>>(w_qkv, wqkvT, 1024, 3072);
  wtrans<<<dim3(16, 16), 256, 0, stream>>>(w_o, woT, 1024, 1024);
  wtrans<<<dim3(64, 16), 256, 0, stream>>>(w_fc1, wfc1T, 1024, 4096);
  wtrans<<<dim3(16, 64), 256, 0, stream>>>(w_fc2, wfc2T, 4096, 1024);

  lnorm<<<2048, 256, 0, stream>>>(x, ln1_g, ln1_b, xn);
  gemm128<0><<<dim3(24, 64), 256, 0, stream>>>(xn, wqkvT, b_qkv, nullptr, qkvb, 3072, 1024, QS, 1024);
  vtrans<<<dim3(16, 128), 256, 0, stream>>>(qkvb, vtb);
  attn64<<<dim3(16, 128), 256, 0, stream>>>(qkvb, vtb, attnb);
  gemm128<2><<<dim3(8, 64), 256, 0, stream>>>(attnb, woT, b_o, x, out, 1024, 1024, 1.f, 0);
  lnorm<<<2048, 256, 0, stream>>>(out, ln2_g, ln2_b, xn);
  gemm128<1><<<dim3(32, 64), 256, 0, stream>>>(xn, wfc1T, b_fc1, nullptr, hbuf, 4096, 1024, 1.f, 0);
  gemm128<2><<<dim3(8, 64), 256, 0, stream>>>(hbuf, wfc2T, b_fc2, out, out, 1024, 4096, 1.f, 0);
}

// Round 4
// 418.785 us; speedup vs baseline: 1.0784x; 1.0784x over previous
//
#include <hip/hip_runtime.h>
#include <stdint.h>

typedef unsigned short u16;
typedef __bf16 bf16x8 __attribute__((ext_vector_type(8)));
typedef float f32x4 __attribute__((ext_vector_type(4)));

#define GLD16(gp, lp) __builtin_amdgcn_global_load_lds( \
    (__attribute__((address_space(1))) void*)(uintptr_t)(gp), \
    (__attribute__((address_space(3))) void*)(uintptr_t)(lp), 16, 0, 0)

#define WAITVM(N) asm volatile("s_waitcnt vmcnt(" #N ")" ::: "memory")
#define BARRIER() asm volatile("s_barrier" ::: "memory")

__device__ __forceinline__ u16 f2bf(float f) {
  uint32_t u = __builtin_bit_cast(uint32_t, f);
  u += 0x7FFFu + ((u >> 16) & 1u);
  return (u16)(u >> 16);
}

// ---------------- weight transpose + convert: w[K][N] f32 -> wt[N][K] bf16 ----------
__global__ __launch_bounds__(256) void wtrans(const float* __restrict__ w,
                                              u16* __restrict__ wt, int K, int Nn) {
  __shared__ float tile[64][68];
  const int c0 = blockIdx.x << 6, r0 = blockIdx.y << 6;
  const int t = threadIdx.x, tr = t >> 2, tc = t & 3;
#pragma unroll
  for (int p = 0; p < 4; ++p) {
    float4 v = *(const float4*)&w[(size_t)(r0 + tr) * Nn + c0 + tc * 4 + p * 16];
    tile[tr][tc * 4 + p * 16 + 0] = v.x;
    tile[tr][tc * 4 + p * 16 + 1] = v.y;
    tile[tr][tc * 4 + p * 16 + 2] = v.z;
    tile[tr][tc * 4 + p * 16 + 3] = v.w;
  }
  __syncthreads();
#pragma unroll
  for (int p = 0; p < 4; ++p) {
    u16 e0 = f2bf(tile[tc * 4 + p * 16 + 0][tr]);
    u16 e1 = f2bf(tile[tc * 4 + p * 16 + 1][tr]);
    u16 e2 = f2bf(tile[tc * 4 + p * 16 + 2][tr]);
    u16 e3 = f2bf(tile[tc * 4 + p * 16 + 3][tr]);
    uint2 o;
    o.x = (uint32_t)e0 | ((uint32_t)e1 << 16);
    o.y = (uint32_t)e2 | ((uint32_t)e3 << 16);
    *(uint2*)&wt[(size_t)(c0 + tr) * K + r0 + tc * 4 + p * 16] = o;
  }
}

// ---------------- LayerNorm: x[M][1024] f32 -> out bf16 ----------------------------
__global__ __launch_bounds__(256) void lnorm(const float* x, const float* __restrict__ g,
                                             const float* __restrict__ bta,
                                             u16* __restrict__ out) {
  const int lane = threadIdx.x & 63, wid = threadIdx.x >> 6;
  const size_t token = (size_t)blockIdx.x * 4 + wid;
  const float* row = x + token * 1024;
  float v[16];
#pragma unroll
  for (int i = 0; i < 4; ++i) {
    float4 f = *(const float4*)&row[(lane + i * 64) * 4];
    v[i * 4 + 0] = f.x; v[i * 4 + 1] = f.y; v[i * 4 + 2] = f.z; v[i * 4 + 3] = f.w;
  }
  float s = 0.f, s2 = 0.f;
#pragma unroll
  for (int i = 0; i < 16; ++i) { s += v[i]; s2 += v[i] * v[i]; }
  for (int off = 1; off < 64; off <<= 1) {
    s += __shfl_xor(s, off);
    s2 += __shfl_xor(s2, off);
  }
  const float mu = s * (1.0f / 1024.0f);
  const float var = s2 * (1.0f / 1024.0f) - mu * mu;
  const float rstd = rsqrtf(var + 1e-6f);
  u16* orow = out + token * 1024;
#pragma unroll
  for (int i = 0; i < 4; ++i) {
    const int c = (lane + i * 64) * 4;
    float4 gv = *(const float4*)&g[c];
    float4 bv = *(const float4*)&bta[c];
    u16 e0 = f2bf((v[i * 4 + 0] - mu) * rstd * gv.x + bv.x);
    u16 e1 = f2bf((v[i * 4 + 1] - mu) * rstd * gv.y + bv.y);
    u16 e2 = f2bf((v[i * 4 + 2] - mu) * rstd * gv.z + bv.z);
    u16 e3 = f2bf((v[i * 4 + 3] - mu) * rstd * gv.w + bv.w);
    uint2 o;
    o.x = (uint32_t)e0 | ((uint32_t)e1 << 16);
    o.y = (uint32_t)e2 | ((uint32_t)e3 << 16);
    *(uint2*)&orow[c] = o;
  }
}

// ---------------- 8-phase-style GEMM: C[M][N] = A*Bt^T + bias ----------------------
// BM=256, 8 waves. BN=256: 2Mx4N waves (128x64/wave); BN=128: 4Mx2N (64x64/wave).
// 3-slot LDS ring, stage K-tile kt+2 during iter kt, 4 phases/K-tile, one barrier
// + one counted vmcnt per K-tile (vmcnt(4)/vmcnt(3); 0 only on the last iter).
// EPI 0: +bias (cols<qlimit scaled) -> bf16; 1: +bias GELU -> bf16; 2: +bias+res -> f32
template <int EPI, int BN>
__global__ __launch_bounds__(512, 2) void gemm256(const u16* __restrict__ A,
                                                  const u16* __restrict__ Bt,
                                                  const float* __restrict__ bias,
                                                  const float* res, void* Cout,
                                                  int Ndim, int K, float qscale,
                                                  int qlimit, int gn) {
  constexpr int MF = (BN == 256) ? 8 : 4;   // m-frags per wave
  constexpr int HMF = MF / 2;
  constexpr int WMS = (BN == 256) ? 128 : 64;  // wave m-stride
  constexpr int SLOT = 8192 + BN * 32;         // u16 per slot (A 16KB + B)
  __shared__ __align__(16) u16 lds[3][SLOT];

  const int tid = threadIdx.x, lane = tid & 63, wid = tid >> 6;
  const int wm = (BN == 256) ? (wid >> 2) : (wid >> 1);
  const int wn = (BN == 256) ? (wid & 3) : (wid & 1);

  // bijective XCD swizzle (gridDim.x % 8 == 0 for all our shapes)
  const int wg = blockIdx.x;
  const int swz = (wg & 7) * ((int)gridDim.x >> 3) + (wg >> 3);
  const int mblk = swz / gn;
  const int nb = swz - mblk * gn;
  const int m0 = mblk << 8;
  const int n0 = nb * BN;

  // staging: thread t covers row t>>2 (0..127 per GLD), phys chunk t&3,
  // logical chunk (t&3) ^ SW(row), SW(r) = (r ^ (r>>2)) & 3
  const int srow = tid >> 2;
  const int slc = (tid & 3) ^ ((srow ^ (srow >> 2)) & 3);
  const u16* Ag = A + (size_t)(m0 + srow) * K + slc * 8;
  const u16* Bg = Bt + (size_t)(n0 + srow) * K + slc * 8;
  const size_t rstep = (size_t)128 * K;

  // fragment reads
  const int rrow = lane & 15;
  const int rc = ((lane >> 4) ^ ((rrow ^ (rrow >> 2)) & 3)) * 16;  // byte
  const int aRow0 = wm * WMS + rrow;
  const int bRow0 = wn * 64 + rrow;

  const f32x4 fzero = {0.f, 0.f, 0.f, 0.f};
  f32x4 acc[MF][4];
#pragma unroll
  for (int i = 0; i < MF; ++i)
#pragma unroll
    for (int j = 0; j < 4; ++j) acc[i][j] = fzero;

  const int nk = K >> 5;

#define SA0(kt, s) GLD16(Ag + (size_t)(kt) * 32, &lds[s][wid * 512])
#define SA1(kt, s) GLD16(Ag + rstep + (size_t)(kt) * 32, &lds[s][4096 + wid * 512])
#define SB0(kt, s) GLD16(Bg + (size_t)(kt) * 32, &lds[s][8192 + wid * 512])
#define SB1(kt, s) GLD16(Bg + rstep + (size_t)(kt) * 32, &lds[s][12288 + wid * 512])

  SA0(0, 0); SA1(0, 0); SB0(0, 0);
  if constexpr (BN == 256) SB1(0, 0);
  SA0(1, 1); SA1(1, 1); SB0(1, 1);
  if constexpr (BN == 256) SB1(1, 1);

  int cs = 0, ss = 2;
  for (int kt = 0; kt < nk; ++kt) {
    if (kt + 1 < nk) {
      if constexpr (BN == 256) WAITVM(4); else WAITVM(3);
    } else {
      WAITVM(0);
    }
    BARRIER();
    const bool pf = (kt + 2 < nk);
    const char* la = (const char*)&lds[cs][0];
    const char* lb = la + 16384;
    bf16x8 af[MF], bv[4];
    // ---- phase 0: m-half0 x n-half0
    if (pf) SA0(kt + 2, ss);
#pragma unroll
    for (int i = 0; i < HMF; ++i)
      af[i] = *(const bf16x8*)(la + (aRow0 + i * 16) * 64 + rc);
    bv[0] = *(const bf16x8*)(lb + (bRow0 + 0) * 64 + rc);
    bv[1] = *(const bf16x8*)(lb + (bRow0 + 16) * 64 + rc);
    __builtin_amdgcn_s_setprio(1);
#pragma unroll
    for (int i = 0; i < HMF; ++i)
#pragma unroll
      for (int j = 0; j < 2; ++j)
        acc[i][j] = __builtin_amdgcn_mfma_f32_16x16x32_bf16(af[i], bv[j], acc[i][j], 0, 0, 0);
    __builtin_amdgcn_s_setprio(0);
    // ---- phase 1: m-half1 x n-half0
    if (pf) SA1(kt + 2, ss);
#pragma unroll
    for (int i = 0; i < HMF; ++i)
      af[HMF + i] = *(const bf16x8*)(la + (aRow0 + (HMF + i) * 16) * 64 + rc);
    __builtin_amdgcn_s_setprio(1);
#pragma unroll
    for (int i = 0; i < HMF; ++i)
#pragma unroll
      for (int j = 0; j < 2; ++j)
        acc[HMF + i][j] =
            __builtin_amdgcn_mfma_f32_16x16x32_bf16(af[HMF + i], bv[j], acc[HMF + i][j], 0, 0, 0);
    __builtin_amdgcn_s_setprio(0);
    // ---- phase 2: m-half1 x n-half1
    if (pf) SB0(kt + 2, ss);
    bv[2] = *(const bf16x8*)(lb + (bRow0 + 32) * 64 + rc);
    bv[3] = *(const bf16x8*)(lb + (bRow0 + 48) * 64 + rc);
    __builtin_amdgcn_s_setprio(1);
#pragma unroll
    for (int i = 0; i < HMF; ++i)
#pragma unroll
      for (int j = 0; j < 2; ++j)
        acc[HMF + i][2 + j] =
            __builtin_amdgcn_mfma_f32_16x16x32_bf16(af[HMF + i], bv[2 + j], acc[HMF + i][2 + j], 0, 0, 0);
    __builtin_amdgcn_s_setprio(0);
    // ---- phase 3: m-half0 x n-half1
    if constexpr (BN == 256) {
      if (pf) SB1(kt + 2, ss);
    }
    __builtin_amdgcn_s_setprio(1);
#pragma unroll
    for (int i = 0; i < HMF; ++i)
#pragma unroll
      for (int j = 0; j < 2; ++j)
        acc[i][2 + j] =
            __builtin_amdgcn_mfma_f32_16x16x32_bf16(af[i], bv[2 + j], acc[i][2 + j], 0, 0, 0);
    __builtin_amdgcn_s_setprio(0);

    cs = (cs == 2) ? 0 : cs + 1;
    ss = (ss == 2) ? 0 : ss + 1;
  }
#undef SA0
#undef SA1
#undef SB0
#undef SB1

  const int g4 = (lane >> 4) << 2;
#pragma unroll
  for (int nf = 0; nf < 4; ++nf) {
    const int col = n0 + wn * 64 + nf * 16 + rrow;
    const float bvb = bias[col];
    const float csf = (EPI == 0 && col < qlimit) ? qscale : 1.0f;
#pragma unroll
    for (int mf = 0; mf < MF; ++mf) {
#pragma unroll
      for (int r = 0; r < 4; ++r) {
        const int row = m0 + wm * WMS + mf * 16 + g4 + r;
        float v = acc[mf][nf][r] + bvb;
        if (EPI == 0) v *= csf;
        if (EPI == 1) v = 0.5f * v * (1.0f + erff(v * 0.70710678118654752f));
        if (EPI == 2) {
          v += res[(size_t)row * Ndim + col];
          ((float*)Cout)[(size_t)row * Ndim + col] = v;
        } else {
          ((u16*)Cout)[(size_t)row * Ndim + col] = f2bf(v);
        }
      }
    }
  }
}

// ---------------- V transpose: qkv V block -> vt[bh][d][n] bf16 --------------------
__global__ __launch_bounds__(256) void vtrans(const u16* __restrict__ qkv,
                                              u16* __restrict__ vt) {
  const int bh = blockIdx.y, b = bh >> 4, h = bh & 15;
  const int n0 = blockIdx.x << 6;
  __shared__ __align__(16) u16 tile[64][72];
  const int t = threadIdx.x, r = t >> 2, c = t & 3;
  const u16* src = qkv + (size_t)((b << 10) + n0 + r) * 3072 + 2048 + (h << 6);
#pragma unroll
  for (int p = 0; p < 2; ++p)
    *(uint4*)&tile[r][(c * 2 + p) * 8] = *(const uint4*)(src + (c * 2 + p) * 8);
  __syncthreads();
  u16* dst = vt + (size_t)((bh << 6) + r) * 1024 + n0;
#pragma unroll
  for (int p = 0; p < 2; ++p) {
    u16 o[8];
#pragma unroll
    for (int j = 0; j < 8; ++j) o[j] = tile[(c * 2 + p) * 8 + j][r];
    uint4 w;
    w.x = (uint32_t)o[0] | ((uint32_t)o[1] << 16);
    w.y = (uint32_t)o[2] | ((uint32_t)o[3] << 16);
    w.z = (uint32_t)o[4] | ((uint32_t)o[5] << 16);
    w.w = (uint32_t)o[6] | ((uint32_t)o[7] << 16);
    *(uint4*)&dst[(c * 2 + p) * 8] = w;
  }
}

// ---------------- flash attention (no-max softmax, swapped QK^T) -------------------
__global__ __launch_bounds__(256) void attn64(const u16* __restrict__ qkv,
                                              const u16* __restrict__ vt,
                                              u16* __restrict__ aout) {
  const int bh = blockIdx.y, b = bh >> 4, h = bh & 15;
  const int q0 = blockIdx.x << 6;
  const int tid = threadIdx.x, lane = tid & 63, wid = tid >> 6;
  __shared__ __align__(16) u16 kl[4096];
  __shared__ __align__(16) u16 vl[4096];
  __shared__ __align__(16) u16 pl[4][1152];  // [wave][16 q][72]: P rows, k-major

  const int rrow = lane & 15;
  const int g = lane >> 4;
  const u16* qrow = qkv + (size_t)((b << 10) + q0 + (wid << 4) + rrow) * 3072 + (h << 6);
  bf16x8 qf0 = *(const bf16x8*)(qrow + (g << 3));
  bf16x8 qf1 = *(const bf16x8*)(qrow + 32 + (g << 3));

  const int sr = lane >> 3;
  const int lc = (lane & 7) ^ sr;
  const u16* kbase = qkv + (size_t)(b << 10) * 3072 + 1024 + (h << 6) +
                     (size_t)(16 * wid + sr) * 3072 + lc * 8;
  const u16* vbase = vt + (size_t)(bh << 6) * 1024 + (size_t)(16 * wid + sr) * 1024 + lc * 8;

  const f32x4 fzero = {0.f, 0.f, 0.f, 0.f};
  f32x4 oacc[4];
#pragma unroll
  for (int i = 0; i < 4; ++i) oacc[i] = fzero;
  f32x4 lacc = fzero;
  const int rcb = lane & 7;
  u16* plw = &pl[wid][0];

  for (int t = 0; t < 16; ++t) {
    const int kt0 = t << 6;
    GLD16(kbase + (size_t)kt0 * 3072, &kl[(2 * wid + 0) * 512]);
    GLD16(kbase + (size_t)kt0 * 3072 + 8 * 3072, &kl[(2 * wid + 1) * 512]);
    GLD16(vbase + kt0, &vl[(2 * wid + 0) * 512]);
    GLD16(vbase + kt0 + 8 * 1024, &vl[(2 * wid + 1) * 512]);
    __syncthreads();

    f32x4 s4[4];
#pragma unroll
    for (int i = 0; i < 4; ++i) s4[i] = fzero;
#pragma unroll
    for (int nf = 0; nf < 4; ++nf) {
      bf16x8 k0 = *(const bf16x8*)((const char*)kl + (nf * 16 + rrow) * 128 +
                                   ((g + 0) ^ rcb) * 16);
      bf16x8 k1 = *(const bf16x8*)((const char*)kl + (nf * 16 + rrow) * 128 +
                                   ((g + 4) ^ rcb) * 16);
      s4[nf] = __builtin_amdgcn_mfma_f32_16x16x32_bf16(k0, qf0, s4[nf], 0, 0, 0);
      s4[nf] = __builtin_amdgcn_mfma_f32_16x16x32_bf16(k1, qf1, s4[nf], 0, 0, 0);
    }

#pragma unroll
    for (int nf = 0; nf < 4; ++nf) {
      float p0 = exp2f(s4[nf][0]);
      float p1 = exp2f(s4[nf][1]);
      float p2 = exp2f(s4[nf][2]);
      float p3 = exp2f(s4[nf][3]);
      f32x4 pv = {p0, p1, p2, p3};
      lacc += pv;
      uint32_t a0 = __builtin_bit_cast(uint32_t, p0) + 0x8000u;
      uint32_t a1 = __builtin_bit_cast(uint32_t, p1) + 0x8000u;
      uint32_t a2 = __builtin_bit_cast(uint32_t, p2) + 0x8000u;
      uint32_t a3 = __builtin_bit_cast(uint32_t, p3) + 0x8000u;
      uint2 w;
      w.x = __builtin_amdgcn_perm(a1, a0, 0x07060302);
      w.y = __builtin_amdgcn_perm(a3, a2, 0x07060302);
      *(uint2*)(plw + rrow * 72 + nf * 16 + (g << 2)) = w;
    }

    bf16x8 pf0 = *(const bf16x8*)((const char*)plw + rrow * 144 + (g << 4));
    bf16x8 pf1 = *(const bf16x8*)((const char*)plw + rrow * 144 + (g << 4) + 64);
#pragma unroll
    for (int nf = 0; nf < 4; ++nf) {
      bf16x8 v0 = *(const bf16x8*)((const char*)vl + (nf * 16 + rrow) * 128 +
                                   ((g + 0) ^ rcb) * 16);
      bf16x8 v1 = *(const bf16x8*)((const char*)vl + (nf * 16 + rrow) * 128 +
                                   ((g + 4) ^ rcb) * 16);
      oacc[nf] = __builtin_amdgcn_mfma_f32_16x16x32_bf16(pf0, v0, oacc[nf], 0, 0, 0);
      oacc[nf] = __builtin_amdgcn_mfma_f32_16x16x32_bf16(pf1, v1, oacc[nf], 0, 0, 0);
    }
    __syncthreads();
  }

  float lsum = lacc[0] + lacc[1] + lacc[2] + lacc[3];
  lsum += __shfl_xor(lsum, 16);
  lsum += __shfl_xor(lsum, 32);
  const float inv = 1.0f / lsum;
  float invq[4];
#pragma unroll
  for (int r = 0; r < 4; ++r) {
    int bi = __builtin_amdgcn_ds_bpermute(((g << 2) + r) << 2,
                                          __builtin_bit_cast(int, inv));
    invq[r] = __builtin_bit_cast(float, bi);
  }
  u16* ob = aout + (size_t)((b << 10) + q0 + (wid << 4)) * 1024 + (h << 6);
#pragma unroll
  for (int nf = 0; nf < 4; ++nf)
#pragma unroll
    for (int r = 0; r < 4; ++r)
      ob[(size_t)(g * 4 + r) * 1024 + nf * 16 + rrow] = f2bf(oacc[nf][r] * invq[r]);
}

// ---------------- launcher ---------------------------------------------------------
extern "C" void kernel_launch(void* const* d_in, const int* in_sizes, int n_in,
                              void* d_out, int out_size, void* d_ws, size_t ws_size,
                              hipStream_t stream) {
  const float* x = (const float*)d_in[0];
  const float* ln1_g = (const float*)d_in[1];
  const float* ln1_b = (const float*)d_in[2];
  const float* w_qkv = (const float*)d_in[3];
  const float* b_qkv = (const float*)d_in[4];
  const float* w_o = (const float*)d_in[5];
  const float* b_o = (const float*)d_in[6];
  const float* ln2_g = (const float*)d_in[7];
  const float* ln2_b = (const float*)d_in[8];
  const float* w_fc1 = (const float*)d_in[9];
  const float* b_fc1 = (const float*)d_in[10];
  const float* w_fc2 = (const float*)d_in[11];
  const float* b_fc2 = (const float*)d_in[12];
  float* out = (float*)d_out;

  char* w = (char*)d_ws;
  u16* wqkvT = (u16*)w; w += (size_t)3072 * 1024 * 2;
  u16* woT   = (u16*)w; w += (size_t)1024 * 1024 * 2;
  u16* wfc1T = (u16*)w; w += (size_t)4096 * 1024 * 2;
  u16* wfc2T = (u16*)w; w += (size_t)1024 * 4096 * 2;
  u16* xn    = (u16*)w; w += (size_t)8192 * 1024 * 2;
  u16* qkvb  = (u16*)w; w += (size_t)8192 * 3072 * 2;
  u16* vtb   = (u16*)w; w += (size_t)128 * 64 * 1024 * 2;
  u16* attnb = (u16*)w; w += (size_t)8192 * 1024 * 2;
  u16* hbuf  = qkvb;  // overlay: qkv+vt dead when h is produced

  const float QS = 0.18033688011112042f;  // 0.125 * log2(e)

  wtrans<<<dim3(48, 16), 256, 0, stream>>>(w_qkv, wqkvT, 1024, 3072);
  wtrans<<<dim3(16, 16), 256, 0, stream>>>(w_o, woT, 1024, 1024);
  wtrans<<<dim3(64, 16), 256, 0, stream>>>(w_fc1, wfc1T, 1024, 4096);
  wtrans<<<dim3(16, 64), 256, 0, stream>>>(w_fc2, wfc2T, 4096, 1024);

  lnorm<<<2048, 256, 0, stream>>>(x, ln1_g, ln1_b, xn);
  gemm256<0, 256><<<384, 512, 0, stream>>>(xn, wqkvT, b_qkv, nullptr, qkvb, 3072, 1024, QS, 1024, 12);
  vtrans<<<dim3(16, 128), 256, 0, stream>>>(qkvb, vtb);
  attn64<<<dim3(16, 128), 256, 0, stream>>>(qkvb, vtb, attnb);
  gemm256<2, 128><<<256, 512, 0, stream>>>(attnb, woT, b_o, x, out, 1024, 1024, 1.f, 0, 8);
  lnorm<<<2048, 256, 0, stream>>>(out, ln2_g, ln2_b, xn);
  gemm256<1, 256><<<512, 512, 0, stream>>>(xn, wfc1T, b_fc1, nullptr, hbuf, 4096, 1024, 1.f, 0, 16);
  gemm256<2, 128><<<256, 512, 0, stream>>>(hbuf, wfc2T, b_fc2, out, out, 1024, 4096, 1.f, 0, 8);
}

// Round 5
// 416.336 us; speedup vs baseline: 1.0847x; 1.0059x over previous
//
#include <hip/hip_runtime.h>
#include <stdint.h>

typedef unsigned short u16;
typedef __bf16 bf16x8 __attribute__((ext_vector_type(8)));
typedef float f32x4 __attribute__((ext_vector_type(4)));

#define GLD16(gp, lp) __builtin_amdgcn_global_load_lds( \
    (__attribute__((address_space(1))) void*)(uintptr_t)(gp), \
    (__attribute__((address_space(3))) void*)(uintptr_t)(lp), 16, 0, 0)

#define WAITVM(N) asm volatile("s_waitcnt vmcnt(" #N ")" ::: "memory")
#define BARRIER() asm volatile("s_barrier" ::: "memory")
#define MM(a, b, c) __builtin_amdgcn_mfma_f32_16x16x32_bf16(a, b, c, 0, 0, 0)

__device__ __forceinline__ u16 f2bf(float f) {
  uint32_t u = __builtin_bit_cast(uint32_t, f);
  u += 0x7FFFu + ((u >> 16) & 1u);
  return (u16)(u >> 16);
}

// ---------------- weight transpose + convert: w[K][N] f32 -> wt[N][K] bf16 ----------
__global__ __launch_bounds__(256) void wtrans(const float* __restrict__ w,
                                              u16* __restrict__ wt, int K, int Nn) {
  __shared__ float tile[64][68];
  const int c0 = blockIdx.x << 6, r0 = blockIdx.y << 6;
  const int t = threadIdx.x, tr = t >> 2, tc = t & 3;
#pragma unroll
  for (int p = 0; p < 4; ++p) {
    float4 v = *(const float4*)&w[(size_t)(r0 + tr) * Nn + c0 + tc * 4 + p * 16];
    tile[tr][tc * 4 + p * 16 + 0] = v.x;
    tile[tr][tc * 4 + p * 16 + 1] = v.y;
    tile[tr][tc * 4 + p * 16 + 2] = v.z;
    tile[tr][tc * 4 + p * 16 + 3] = v.w;
  }
  __syncthreads();
#pragma unroll
  for (int p = 0; p < 4; ++p) {
    u16 e0 = f2bf(tile[tc * 4 + p * 16 + 0][tr]);
    u16 e1 = f2bf(tile[tc * 4 + p * 16 + 1][tr]);
    u16 e2 = f2bf(tile[tc * 4 + p * 16 + 2][tr]);
    u16 e3 = f2bf(tile[tc * 4 + p * 16 + 3][tr]);
    uint2 o;
    o.x = (uint32_t)e0 | ((uint32_t)e1 << 16);
    o.y = (uint32_t)e2 | ((uint32_t)e3 << 16);
    *(uint2*)&wt[(size_t)(c0 + tr) * K + r0 + tc * 4 + p * 16] = o;
  }
}

// ---------------- LayerNorm: x[M][1024] f32 -> out bf16 ----------------------------
__global__ __launch_bounds__(256) void lnorm(const float* x, const float* __restrict__ g,
                                             const float* __restrict__ bta,
                                             u16* __restrict__ out) {
  const int lane = threadIdx.x & 63, wid = threadIdx.x >> 6;
  const size_t token = (size_t)blockIdx.x * 4 + wid;
  const float* row = x + token * 1024;
  float v[16];
#pragma unroll
  for (int i = 0; i < 4; ++i) {
    float4 f = *(const float4*)&row[(lane + i * 64) * 4];
    v[i * 4 + 0] = f.x; v[i * 4 + 1] = f.y; v[i * 4 + 2] = f.z; v[i * 4 + 3] = f.w;
  }
  float s = 0.f, s2 = 0.f;
#pragma unroll
  for (int i = 0; i < 16; ++i) { s += v[i]; s2 += v[i] * v[i]; }
  for (int off = 1; off < 64; off <<= 1) {
    s += __shfl_xor(s, off);
    s2 += __shfl_xor(s2, off);
  }
  const float mu = s * (1.0f / 1024.0f);
  const float var = s2 * (1.0f / 1024.0f) - mu * mu;
  const float rstd = rsqrtf(var + 1e-6f);
  u16* orow = out + token * 1024;
#pragma unroll
  for (int i = 0; i < 4; ++i) {
    const int c = (lane + i * 64) * 4;
    float4 gv = *(const float4*)&g[c];
    float4 bv = *(const float4*)&bta[c];
    u16 e0 = f2bf((v[i * 4 + 0] - mu) * rstd * gv.x + bv.x);
    u16 e1 = f2bf((v[i * 4 + 1] - mu) * rstd * gv.y + bv.y);
    u16 e2 = f2bf((v[i * 4 + 2] - mu) * rstd * gv.z + bv.z);
    u16 e3 = f2bf((v[i * 4 + 3] - mu) * rstd * gv.w + bv.w);
    uint2 o;
    o.x = (uint32_t)e0 | ((uint32_t)e1 << 16);
    o.y = (uint32_t)e2 | ((uint32_t)e3 << 16);
    *(uint2*)&orow[c] = o;
  }
}

// ---------------- pipelined GEMM (m201-style scaled): C = A[M][K] * Bt[N][K]^T ------
// BM=256 BN=128 BK=32, 8 waves (wave-tile 64x64), 4-slot LDS ring (96 KB).
// Phase t: {8 ds_read (tile t) ; stage tile t+3 (3 GLD16) ; vmcnt(6) ; barrier ;
//           16 MFMA (setprio-wrapped) ; barrier}.
// Invariant entering phase p: S(p) landed+published (phase p-1 retired it),
// outstanding = S(p+1),S(p+2) (6 loads). Phase p issues S(p+3) -> 9, vmcnt(6)
// retires S(p+1) (issued 2 phases earlier -> latency hidden). WAR: stage into
// slot (p+3)&3 = (p-1)&3, last read at phase p-1 whose closing barrier precedes
// the stage issue. Peeled tail phases drain 6 -> 3 -> 0.
// LDS tile layout: row-major [rows][4 chunks of 16B], phys_chunk = c ^ ((row>>1)&3)
// (64-lane b128 read -> exactly 8 accesses/bank, optimal). DMA dest linear,
// global source pre-swizzled.
template <int EPI>
__global__ __launch_bounds__(512, 2) void gemmp(const u16* __restrict__ A,
                                                const u16* __restrict__ Bt,
                                                const float* __restrict__ bias,
                                                const float* res, void* Cout,
                                                int Ndim, int K, float qscale,
                                                int qlimit, int gn) {
  __shared__ __align__(16) u16 lds[4][12288];  // slot = A 16KB + B 8KB
  const int tid = threadIdx.x, lane = tid & 63, wid = tid >> 6;
  const int wm = wid >> 1, wn = wid & 1;

  const int wg = blockIdx.x;
  const int swz = (wg & 7) * ((int)gridDim.x >> 3) + (wg >> 3);
  const int mblk = swz / gn, nb = swz - mblk * gn;
  const int m0 = mblk << 8, n0 = nb << 7;

  // staging: thread t -> row (t>>2) [+128 for A instr1], phys chunk t&3,
  // logical chunk sc = (t&3) ^ ((t>>3)&3)  (= phys ^ swizzle(row))
  const int srow = tid >> 2;
  const int sc = (tid & 3) ^ ((tid >> 3) & 3);
  const u16* Ag0 = A + (size_t)(m0 + srow) * K + sc * 8;
  const u16* Ag1 = Ag0 + (size_t)128 * K;
  const u16* Bg = Bt + (size_t)(n0 + srow) * K + sc * 8;

  u16* lb = &lds[0][0];
  // fragment read pointers (per slot): row = base + rrow, phys = g ^ ((rrow>>1)&3)
  const int rrow = lane & 15, g = lane >> 4;
  const int xg = g ^ ((rrow >> 1) & 3);
  const int aoff = (wm * 64 + rrow) * 64 + xg * 16;           // bytes
  const int boff = 16384 + (wn * 64 + rrow) * 64 + xg * 16;   // bytes
  const char* pA[4];
  const char* pB[4];
#pragma unroll
  for (int s = 0; s < 4; ++s) {
    pA[s] = (const char*)lb + s * 24576 + aoff;
    pB[s] = (const char*)lb + s * 24576 + boff;
  }

  const f32x4 fzero = {0.f, 0.f, 0.f, 0.f};
  f32x4 acc[4][4];
#pragma unroll
  for (int i = 0; i < 4; ++i)
#pragma unroll
    for (int j = 0; j < 4; ++j) acc[i][j] = fzero;

#define STG(tt, ss) do { \
    GLD16(Ag0 + (tt) * 32, lb + (ss) * 12288 + wid * 512); \
    GLD16(Ag1 + (tt) * 32, lb + (ss) * 12288 + 4096 + wid * 512); \
    GLD16(Bg + (tt) * 32, lb + (ss) * 12288 + 8192 + wid * 512); \
  } while (0)

#define PH(dt, DOSTG, WVA) do { \
    bf16x8 af0 = *(const bf16x8*)(pA[(dt)] + 0); \
    bf16x8 af1 = *(const bf16x8*)(pA[(dt)] + 1024); \
    bf16x8 af2 = *(const bf16x8*)(pA[(dt)] + 2048); \
    bf16x8 af3 = *(const bf16x8*)(pA[(dt)] + 3072); \
    bf16x8 bf0 = *(const bf16x8*)(pB[(dt)] + 0); \
    bf16x8 bf1 = *(const bf16x8*)(pB[(dt)] + 1024); \
    bf16x8 bf2 = *(const bf16x8*)(pB[(dt)] + 2048); \
    bf16x8 bf3 = *(const bf16x8*)(pB[(dt)] + 3072); \
    if (DOSTG) STG((dt) + 3, ((dt) + 3) & 3); \
    WVA; \
    BARRIER(); \
    __builtin_amdgcn_s_setprio(1); \
    acc[0][0] = MM(af0, bf0, acc[0][0]); \
    acc[1][0] = MM(af1, bf0, acc[1][0]); \
    acc[2][0] = MM(af2, bf0, acc[2][0]); \
    acc[3][0] = MM(af3, bf0, acc[3][0]); \
    acc[0][1] = MM(af0, bf1, acc[0][1]); \
    acc[1][1] = MM(af1, bf1, acc[1][1]); \
    acc[2][1] = MM(af2, bf1, acc[2][1]); \
    acc[3][1] = MM(af3, bf1, acc[3][1]); \
    acc[0][2] = MM(af0, bf2, acc[0][2]); \
    acc[1][2] = MM(af1, bf2, acc[1][2]); \
    acc[2][2] = MM(af2, bf2, acc[2][2]); \
    acc[3][2] = MM(af3, bf2, acc[3][2]); \
    acc[0][3] = MM(af0, bf3, acc[0][3]); \
    acc[1][3] = MM(af1, bf3, acc[1][3]); \
    acc[2][3] = MM(af2, bf3, acc[2][3]); \
    acc[3][3] = MM(af3, bf3, acc[3][3]); \
    __builtin_amdgcn_s_setprio(0); \
    BARRIER(); \
  } while (0)

  const int nT = K >> 5;  // K-tiles of 32 (always a multiple of 4 here)
  STG(0, 0);
  STG(1, 1);
  STG(2, 2);
  WAITVM(6);   // S(0) landed
  BARRIER();   // published
  const int nG = nT >> 2;
  for (int gi = 0; gi < nG - 1; ++gi) {
    PH(0, true, WAITVM(6));
    PH(1, true, WAITVM(6));
    PH(2, true, WAITVM(6));
    PH(3, true, WAITVM(6));
    Ag0 += 128;
    Ag1 += 128;
    Bg += 128;
  }
  PH(0, true, WAITVM(6));
  PH(1, false, WAITVM(3));
  PH(2, false, WAITVM(0));
  PH(3, false, (void)0);
#undef PH
#undef STG

  const int g4 = (lane >> 4) << 2;
#pragma unroll
  for (int nf = 0; nf < 4; ++nf) {
    const int col = n0 + wn * 64 + nf * 16 + rrow;
    const float bvb = bias[col];
    const float csf = (EPI == 0 && col < qlimit) ? qscale : 1.0f;
#pragma unroll
    for (int mf = 0; mf < 4; ++mf) {
#pragma unroll
      for (int r = 0; r < 4; ++r) {
        const int row = m0 + wm * 64 + mf * 16 + g4 + r;
        float v = acc[mf][nf][r] + bvb;
        if (EPI == 0) v *= csf;
        if (EPI == 1) v = 0.5f * v * (1.0f + erff(v * 0.70710678118654752f));
        if (EPI == 2) {
          v += res[(size_t)row * Ndim + col];
          ((float*)Cout)[(size_t)row * Ndim + col] = v;
        } else {
          ((u16*)Cout)[(size_t)row * Ndim + col] = f2bf(v);
        }
      }
    }
  }
}

// ---------------- V transpose: qkv V block -> vt[bh][d][n] bf16 --------------------
__global__ __launch_bounds__(256) void vtrans(const u16* __restrict__ qkv,
                                              u16* __restrict__ vt) {
  const int bh = blockIdx.y, b = bh >> 4, h = bh & 15;
  const int n0 = blockIdx.x << 6;
  __shared__ __align__(16) u16 tile[64][72];
  const int t = threadIdx.x, r = t >> 2, c = t & 3;
  const u16* src = qkv + (size_t)((b << 10) + n0 + r) * 3072 + 2048 + (h << 6);
#pragma unroll
  for (int p = 0; p < 2; ++p)
    *(uint4*)&tile[r][(c * 2 + p) * 8] = *(const uint4*)(src + (c * 2 + p) * 8);
  __syncthreads();
  u16* dst = vt + (size_t)((bh << 6) + r) * 1024 + n0;
#pragma unroll
  for (int p = 0; p < 2; ++p) {
    u16 o[8];
#pragma unroll
    for (int j = 0; j < 8; ++j) o[j] = tile[(c * 2 + p) * 8 + j][r];
    uint4 w;
    w.x = (uint32_t)o[0] | ((uint32_t)o[1] << 16);
    w.y = (uint32_t)o[2] | ((uint32_t)o[3] << 16);
    w.z = (uint32_t)o[4] | ((uint32_t)o[5] << 16);
    w.w = (uint32_t)o[6] | ((uint32_t)o[7] << 16);
    *(uint4*)&dst[(c * 2 + p) * 8] = w;
  }
}

// ---------------- flash attention (no-max softmax, swapped QK^T) -------------------
__global__ __launch_bounds__(256) void attn64(const u16* __restrict__ qkv,
                                              const u16* __restrict__ vt,
                                              u16* __restrict__ aout) {
  const int bh = blockIdx.y, b = bh >> 4, h = bh & 15;
  const int q0 = blockIdx.x << 6;
  const int tid = threadIdx.x, lane = tid & 63, wid = tid >> 6;
  __shared__ __align__(16) u16 kl[4096];
  __shared__ __align__(16) u16 vl[4096];
  __shared__ __align__(16) u16 pl[4][1152];  // [wave][16 q][72]: P rows, k-major

  const int rrow = lane & 15;
  const int g = lane >> 4;
  const u16* qrow = qkv + (size_t)((b << 10) + q0 + (wid << 4) + rrow) * 3072 + (h << 6);
  bf16x8 qf0 = *(const bf16x8*)(qrow + (g << 3));
  bf16x8 qf1 = *(const bf16x8*)(qrow + 32 + (g << 3));

  const int sr = lane >> 3;
  const int lc = (lane & 7) ^ sr;
  const u16* kbase = qkv + (size_t)(b << 10) * 3072 + 1024 + (h << 6) +
                     (size_t)(16 * wid + sr) * 3072 + lc * 8;
  const u16* vbase = vt + (size_t)(bh << 6) * 1024 + (size_t)(16 * wid + sr) * 1024 + lc * 8;

  const f32x4 fzero = {0.f, 0.f, 0.f, 0.f};
  f32x4 oacc[4];
#pragma unroll
  for (int i = 0; i < 4; ++i) oacc[i] = fzero;
  f32x4 lacc = fzero;
  const int rcb = lane & 7;
  u16* plw = &pl[wid][0];

  for (int t = 0; t < 16; ++t) {
    const int kt0 = t << 6;
    GLD16(kbase + (size_t)kt0 * 3072, &kl[(2 * wid + 0) * 512]);
    GLD16(kbase + (size_t)kt0 * 3072 + 8 * 3072, &kl[(2 * wid + 1) * 512]);
    GLD16(vbase + kt0, &vl[(2 * wid + 0) * 512]);
    GLD16(vbase + kt0 + 8 * 1024, &vl[(2 * wid + 1) * 512]);
    __syncthreads();

    f32x4 s4[4];
#pragma unroll
    for (int i = 0; i < 4; ++i) s4[i] = fzero;
#pragma unroll
    for (int nf = 0; nf < 4; ++nf) {
      bf16x8 k0 = *(const bf16x8*)((const char*)kl + (nf * 16 + rrow) * 128 +
                                   ((g + 0) ^ rcb) * 16);
      bf16x8 k1 = *(const bf16x8*)((const char*)kl + (nf * 16 + rrow) * 128 +
                                   ((g + 4) ^ rcb) * 16);
      s4[nf] = __builtin_amdgcn_mfma_f32_16x16x32_bf16(k0, qf0, s4[nf], 0, 0, 0);
      s4[nf] = __builtin_amdgcn_mfma_f32_16x16x32_bf16(k1, qf1, s4[nf], 0, 0, 0);
    }

#pragma unroll
    for (int nf = 0; nf < 4; ++nf) {
      float p0 = exp2f(s4[nf][0]);
      float p1 = exp2f(s4[nf][1]);
      float p2 = exp2f(s4[nf][2]);
      float p3 = exp2f(s4[nf][3]);
      f32x4 pv = {p0, p1, p2, p3};
      lacc += pv;
      uint32_t a0 = __builtin_bit_cast(uint32_t, p0) + 0x8000u;
      uint32_t a1 = __builtin_bit_cast(uint32_t, p1) + 0x8000u;
      uint32_t a2 = __builtin_bit_cast(uint32_t, p2) + 0x8000u;
      uint32_t a3 = __builtin_bit_cast(uint32_t, p3) + 0x8000u;
      uint2 w;
      w.x = __builtin_amdgcn_perm(a1, a0, 0x07060302);
      w.y = __builtin_amdgcn_perm(a3, a2, 0x07060302);
      *(uint2*)(plw + rrow * 72 + nf * 16 + (g << 2)) = w;
    }

    bf16x8 pf0 = *(const bf16x8*)((const char*)plw + rrow * 144 + (g << 4));
    bf16x8 pf1 = *(const bf16x8*)((const char*)plw + rrow * 144 + (g << 4) + 64);
#pragma unroll
    for (int nf = 0; nf < 4; ++nf) {
      bf16x8 v0 = *(const bf16x8*)((const char*)vl + (nf * 16 + rrow) * 128 +
                                   ((g + 0) ^ rcb) * 16);
      bf16x8 v1 = *(const bf16x8*)((const char*)vl + (nf * 16 + rrow) * 128 +
                                   ((g + 4) ^ rcb) * 16);
      oacc[nf] = __builtin_amdgcn_mfma_f32_16x16x32_bf16(pf0, v0, oacc[nf], 0, 0, 0);
      oacc[nf] = __builtin_amdgcn_mfma_f32_16x16x32_bf16(pf1, v1, oacc[nf], 0, 0, 0);
    }
    __syncthreads();
  }

  float lsum = lacc[0] + lacc[1] + lacc[2] + lacc[3];
  lsum += __shfl_xor(lsum, 16);
  lsum += __shfl_xor(lsum, 32);
  const float inv = 1.0f / lsum;
  float invq[4];
#pragma unroll
  for (int r = 0; r < 4; ++r) {
    int bi = __builtin_amdgcn_ds_bpermute(((g << 2) + r) << 2,
                                          __builtin_bit_cast(int, inv));
    invq[r] = __builtin_bit_cast(float, bi);
  }
  u16* ob = aout + (size_t)((b << 10) + q0 + (wid << 4)) * 1024 + (h << 6);
#pragma unroll
  for (int nf = 0; nf < 4; ++nf)
#pragma unroll
    for (int r = 0; r < 4; ++r)
      ob[(size_t)(g * 4 + r) * 1024 + nf * 16 + rrow] = f2bf(oacc[nf][r] * invq[r]);
}

// ---------------- launcher ---------------------------------------------------------
extern "C" void kernel_launch(void* const* d_in, const int* in_sizes, int n_in,
                              void* d_out, int out_size, void* d_ws, size_t ws_size,
                              hipStream_t stream) {
  const float* x = (const float*)d_in[0];
  const float* ln1_g = (const float*)d_in[1];
  const float* ln1_b = (const float*)d_in[2];
  const float* w_qkv = (const float*)d_in[3];
  const float* b_qkv = (const float*)d_in[4];
  const float* w_o = (const float*)d_in[5];
  const float* b_o = (const float*)d_in[6];
  const float* ln2_g = (const float*)d_in[7];
  const float* ln2_b = (const float*)d_in[8];
  const float* w_fc1 = (const float*)d_in[9];
  const float* b_fc1 = (const float*)d_in[10];
  const float* w_fc2 = (const float*)d_in[11];
  const float* b_fc2 = (const float*)d_in[12];
  float* out = (float*)d_out;

  char* w = (char*)d_ws;
  u16* wqkvT = (u16*)w; w += (size_t)3072 * 1024 * 2;
  u16* woT   = (u16*)w; w += (size_t)1024 * 1024 * 2;
  u16* wfc1T = (u16*)w; w += (size_t)4096 * 1024 * 2;
  u16* wfc2T = (u16*)w; w += (size_t)1024 * 4096 * 2;
  u16* xn    = (u16*)w; w += (size_t)8192 * 1024 * 2;
  u16* qkvb  = (u16*)w; w += (size_t)8192 * 3072 * 2;
  u16* vtb   = (u16*)w; w += (size_t)128 * 64 * 1024 * 2;
  u16* attnb = (u16*)w; w += (size_t)8192 * 1024 * 2;
  u16* hbuf  = qkvb;  // overlay: qkv+vt dead when h is produced

  const float QS = 0.18033688011112042f;  // 0.125 * log2(e)

  wtrans<<<dim3(48, 16), 256, 0, stream>>>(w_qkv, wqkvT, 1024, 3072);
  wtrans<<<dim3(16, 16), 256, 0, stream>>>(w_o, woT, 1024, 1024);
  wtrans<<<dim3(64, 16), 256, 0, stream>>>(w_fc1, wfc1T, 1024, 4096);
  wtrans<<<dim3(16, 64), 256, 0, stream>>>(w_fc2, wfc2T, 4096, 1024);

  lnorm<<<2048, 256, 0, stream>>>(x, ln1_g, ln1_b, xn);
  gemmp<0><<<768, 512, 0, stream>>>(xn, wqkvT, b_qkv, nullptr, qkvb, 3072, 1024, QS, 1024, 24);
  vtrans<<<dim3(16, 128), 256, 0, stream>>>(qkvb, vtb);
  attn64<<<dim3(16, 128), 256, 0, stream>>>(qkvb, vtb, attnb);
  gemmp<2><<<256, 512, 0, stream>>>(attnb, woT, b_o, x, out, 1024, 1024, 1.f, 0, 8);
  lnorm<<<2048, 256, 0, stream>>>(out, ln2_g, ln2_b, xn);
  gemmp<1><<<1024, 512, 0, stream>>>(xn, wfc1T, b_fc1, nullptr, hbuf, 4096, 1024, 1.f, 0, 32);
  gemmp<2><<<256, 512, 0, stream>>>(hbuf, wfc2T, b_fc2, out, out, 1024, 4096, 1.f, 0, 8);
}